// Round 1
// baseline (495.599 us; speedup 1.0000x reference)
//
#include <hip/hip_runtime.h>
#include <stdint.h>

// Problem constants
#define B_    256
#define T_    512
#define DIN   512
#define H_    512
#define NEMB_ 96
#define BT    131072   // B_*T_
#define KG    1120     // gates GEMM K = 512 + 96 + 512  (70 chunks of 16)

typedef __attribute__((ext_vector_type(8))) short short8;    // 8 bf16 (4 VGPRs)
typedef __attribute__((ext_vector_type(4))) float f32x4;
typedef __attribute__((ext_vector_type(16))) float f32x16;

__device__ __forceinline__ unsigned bf16_rne(float f) {
    unsigned u = __float_as_uint(f);
    return (u + 0x7FFF + ((u >> 16) & 1)) >> 16;
}
__device__ __forceinline__ unsigned pack2(float a, float b) {
    return bf16_rne(a) | (bf16_rne(b) << 16);
}
__device__ __forceinline__ uint4 pack8(float4 f0, float4 f1) {
    uint4 u;
    u.x = pack2(f0.x, f0.y); u.y = pack2(f0.z, f0.w);
    u.z = pack2(f1.x, f1.y); u.w = pack2(f1.z, f1.w);
    return u;
}
__device__ __forceinline__ float tanh_fast(float x) {
    float ex = __expf(2.f * x);
    return 1.f - 2.f / (ex + 1.f);
}
__device__ __forceinline__ float sigmoid_fast(float x) {
    return 1.f / (1.f + __expf(-x));
}

// ---- kernel 0: Wi2h fp32 -> bf16 in MFMA B-fragment order -------------------
// Wbf[nt][c][lane] (short8): value = Wi2h[nt*32 + (lane&31)][(c*2 + (lane>>5))*8 + j]
__global__ void k_bswz(const float* __restrict__ W, uint4* __restrict__ Wbf) {
    int u = blockIdx.x * 256 + threadIdx.x;          // 0..32767
    int l = u & 63, c = (u >> 6) & 31, nt = u >> 11;
    int row = nt * 32 + (l & 31);
    int k0 = (c * 2 + (l >> 5)) * 8;
    const float4* W4 = (const float4*)(W + (size_t)row * 512 + k0);
    Wbf[u] = pack8(W4[0], W4[1]);
}

// ---- kernel 1: prevproj = h @ Wh2h^T + bh2h ---------------------------------
__global__ void k_prevproj(const float* __restrict__ hin, const float* __restrict__ Whh,
                           const float* __restrict__ bh, float* __restrict__ pp) {
    __shared__ float hs[512];
    int b = blockIdx.x >> 4, tc = blockIdx.x & 15;
    int tid = threadIdx.x;
    hs[tid]       = hin[b * 512 + tid];
    hs[256 + tid] = hin[b * 512 + 256 + tid];
    __syncthreads();
    int wave = tid >> 6, lane = tid & 63;
    int o = lane >> 3, kg = lane & 7;
    int t = tc * 32 + wave * 8 + o;
    const float4* wr = (const float4*)(Whh + (size_t)t * 512);
    const float4* hv = (const float4*)hs;
    float acc = 0.f;
#pragma unroll
    for (int j = 0; j < 16; ++j) {
        float4 w = wr[j * 8 + kg];
        float4 x = hv[j * 8 + kg];
        acc += w.x * x.x + w.y * x.y + w.z * x.z + w.w * x.w;
    }
#pragma unroll
    for (int off = 1; off < 8; off <<= 1) acc += __shfl_xor(acc, off, 8);
    if (kg == 0) pp[b * 512 + t] = acc + bh[t];
}

// ---- kernel 2: FUSED scores + exp + context-partial -------------------------
// Per block: 64 t-rows of one batch b.
//   e[t]   = sum_h ws[h] * tanh(GEMM + pp[b,h])      (swapped-operand MFMA:
//            D = mfma(Wfrag, Atile) puts t in lanes, h in regs -> h-reduce is
//            16 in-lane FMAs + one shfl_xor(32) instead of 160 shuffles)
//   p[t]   = exp(e[t])            (no max-sub: |e| <= ||ws||_1 ~ 8, fp32-safe)
//   ctxp[blk][d] = sum_t p[t] * A[t][d]   (re-reads own 128KB tile, L2-hot, fp32)
//   sblk[blk] = sum_t p[t]
__launch_bounds__(512, 4)
__global__ void k_scores(const float* __restrict__ A,              // batch_H [BT,512]
                         const uint4* __restrict__ Wbf,            // frag Wi2h
                         const float* __restrict__ pp,             // [B_,512]
                         const float* __restrict__ wsc,            // Wscore [512]
                         float* __restrict__ e,                    // [BT] (alpha buf)
                         float* __restrict__ ctxp,                 // [2048][512]
                         float* __restrict__ sblk)                 // [2048]
{
    __shared__ uint4 ldsA[4096];                                   // 65536 B (A tile; reused as part[])
    __shared__ float es[8][64];
    __shared__ float wts[64];
    __shared__ float pps[512];
    __shared__ float wss[512];
    int tid = threadIdx.x;
    int blockRow = blockIdx.x * 64;
    int b = blockRow >> 9;                                         // 8 blocks per batch row
    int lane = tid & 63, wave = tid >> 6;
    int l31 = lane & 31, lh = lane >> 5, l7 = lane & 7;

    // phase 1: stage A tile (bf16, swizzled) + pp/ws into LDS
    pps[tid] = pp[b * 512 + tid];
    wss[tid] = wsc[tid];
    const float4* A4 = (const float4*)A;
#pragma unroll
    for (int it = 0; it < 8; ++it) {
        int row = it * 8 + wave;
        size_t gidx = (size_t)(blockRow + row) * 128 + (size_t)lane * 2;
        float4 f0 = A4[gidx], f1 = A4[gidx + 1];
        ldsA[row * 64 + (lane ^ (row & 7))] = pack8(f0, f1);
    }
    __syncthreads();

    // phase 2: MFMA main loop (operands swapped vs. classic: D = W x A^T)
    const short8* lds8 = (const short8*)ldsA;
    int base0 = l31 * 64;
    int base1 = (32 + l31) * 64;
    const short8* wf = (const short8*)Wbf + wave * 4096 + lane;    // h tiles 2w,2w+1
    f32x16 aH0T0 = {0.f}, aH0T1 = {0.f}, aH1T0 = {0.f}, aH1T1 = {0.f};
#pragma unroll
    for (int c = 0; c < 32; ++c) {
        int g = c * 2 + lh;
        int gx = g ^ l7;
        short8 a0 = lds8[base0 + gx];
        short8 a1 = lds8[base1 + gx];
        short8 b0 = wf[c * 64];                       // h tile 2w, chunk c
        short8 b1 = wf[2048 + c * 64];                // h tile 2w+1
        aH0T0 = __builtin_amdgcn_mfma_f32_32x32x16_bf16(b0, a0, aH0T0, 0, 0, 0);
        aH0T1 = __builtin_amdgcn_mfma_f32_32x32x16_bf16(b0, a1, aH0T1, 0, 0, 0);
        aH1T0 = __builtin_amdgcn_mfma_f32_32x32x16_bf16(b1, a0, aH1T0, 0, 0, 0);
        aH1T1 = __builtin_amdgcn_mfma_f32_32x32x16_bf16(b1, a1, aH1T1, 0, 0, 0);
    }

    // phase 3: tanh + weighted h-reduction (h is in regs; t = lane)
    // D layout: col(lane&31) = t, row = (r&3)+8*(r>>2)+4*lh = h_local
    int hb = wave * 64 + 4 * lh;
    float vA = 0.f, vB = 0.f;
#pragma unroll
    for (int r = 0; r < 16; ++r) {
        int h0 = hb + (r & 3) + 8 * (r >> 2);
        float p0 = pps[h0],      w0 = wss[h0];
        float p1 = pps[h0 + 32], w1 = wss[h0 + 32];
        vA += tanh_fast(aH0T0[r] + p0) * w0 + tanh_fast(aH1T0[r] + p1) * w1;
        vB += tanh_fast(aH0T1[r] + p0) * w0 + tanh_fast(aH1T1[r] + p1) * w1;
    }
    vA += __shfl_xor(vA, 32, 64);                    // combine lh halves
    vB += __shfl_xor(vB, 32, 64);
    es[wave][lane] = (lane < 32) ? vA : vB;          // [wave][t_local]
    __syncthreads();

    // phase 4: cross-wave e sum, exp, block denominator (one wave)
    if (tid < 64) {
        float ev = 0.f;
#pragma unroll
        for (int w = 0; w < 8; ++w) ev += es[w][tid];
        e[blockRow + tid] = ev;
        float pexp = __expf(ev);
        wts[tid] = pexp;
        float s = pexp;
#pragma unroll
        for (int off = 1; off < 64; off <<= 1) s += __shfl_xor(s, off, 64);
        if (tid == 0) sblk[blockIdx.x] = s;
    }
    __syncthreads();

    // phase 5: context partial. Wave w handles 8 t-rows; re-read fp32 A (L2-hot).
    float* part = (float*)ldsA;                      // ldsA is dead now
    {
        int t0 = wave * 8;
        float4 c0 = {0.f, 0.f, 0.f, 0.f}, c1 = {0.f, 0.f, 0.f, 0.f};
        size_t rb = (size_t)(blockRow + t0) * 128;
#pragma unroll
        for (int i = 0; i < 8; ++i) {
            float wv = wts[t0 + i];                  // wave-uniform
            float4 x0 = A4[rb + (size_t)i * 128 + lane];
            float4 x1 = A4[rb + (size_t)i * 128 + 64 + lane];
            c0.x += wv * x0.x; c0.y += wv * x0.y; c0.z += wv * x0.z; c0.w += wv * x0.w;
            c1.x += wv * x1.x; c1.y += wv * x1.y; c1.z += wv * x1.z; c1.w += wv * x1.w;
        }
        ((float4*)part)[wave * 128 + lane]      = c0;   // d = lane*4
        ((float4*)part)[wave * 128 + 64 + lane] = c1;   // d = 256 + lane*4
    }
    __syncthreads();
    {
        float s = 0.f;
#pragma unroll
        for (int w = 0; w < 8; ++w) s += part[w * 512 + tid];
        ctxp[(size_t)blockIdx.x * 512 + tid] = s;
    }
}

// ---- kernel 3: alpha = exp(e) / denom; also publish 1/denom per batch -------
__global__ void k_alpha(const float* __restrict__ sblk, float* __restrict__ ealpha,
                        float* __restrict__ invd) {
    int i = blockIdx.x * 256 + threadIdx.x;          // 131072
    int b = i >> 9;
    const float* sb = sblk + b * 8;
    float s = (sb[0] + sb[1]) + (sb[2] + sb[3]) + (sb[4] + sb[5]) + (sb[6] + sb[7]);
    float inv = 1.f / s;
    ealpha[i] = __expf(ealpha[i]) * inv;
    if ((i & 511) == 0) invd[b] = inv;
}

// ---- kernel 5a: xbf = bf16 fragments of [ctx | onehot | h]  -----------------
// ctx is materialized here: ctx[row][d] = invd[row] * sum_q ctxp[row*8+q][d]
__global__ void k_xcat(const float* __restrict__ ctxp, const float* __restrict__ invd,
                       const float* __restrict__ oneh, const float* __restrict__ hin,
                       uint4* __restrict__ xbf) {
    int u = blockIdx.x * 256 + threadIdx.x;          // 0..35839
    int l = u & 63, r = u >> 6;
    int c = r % 70, bt = r / 70;
    int row = bt * 32 + (l & 31);
    int k0 = (c * 2 + (l >> 5)) * 8;
    float4 f0, f1;
    if (k0 < 512) {
        const float4* p4 = (const float4*)(ctxp + (size_t)row * 4096 + k0);
        float4 a = {0.f, 0.f, 0.f, 0.f}, bq = {0.f, 0.f, 0.f, 0.f};
#pragma unroll
        for (int q = 0; q < 8; ++q) {
            float4 s0 = p4[q * 128];
            float4 s1 = p4[q * 128 + 1];
            a.x += s0.x;  a.y += s0.y;  a.z += s0.z;  a.w += s0.w;
            bq.x += s1.x; bq.y += s1.y; bq.z += s1.z; bq.w += s1.w;
        }
        float inv = invd[row];
        f0.x = a.x * inv;  f0.y = a.y * inv;  f0.z = a.z * inv;  f0.w = a.w * inv;
        f1.x = bq.x * inv; f1.y = bq.y * inv; f1.z = bq.z * inv; f1.w = bq.w * inv;
    } else if (k0 < 608) {
        const float4* s4 = (const float4*)(oneh + (size_t)row * 96 + (k0 - 512));
        f0 = s4[0]; f1 = s4[1];
    } else {
        const float4* s4 = (const float4*)(hin + (size_t)row * 512 + (k0 - 608));
        f0 = s4[0]; f1 = s4[1];
    }
    xbf[u] = pack8(f0, f1);
}

// ---- kernel 5b: wgf = bf16 fragments of [W_ih | W_hh]  ----------------------
__global__ void k_wcat(const float* __restrict__ Wih, const float* __restrict__ Whh,
                       uint4* __restrict__ wgf) {
    int u = blockIdx.x * 256 + threadIdx.x;          // 0..286719
    int l = u & 63, r = u >> 6;
    int c = r % 70, gt = r / 70;
    int g = gt * 32 + (l & 31);
    int k0 = (c * 2 + (l >> 5)) * 8;
    const float4* s4;
    if (k0 < 608) s4 = (const float4*)(Wih + (size_t)g * 608 + k0);
    else          s4 = (const float4*)(Whh + (size_t)g * 512 + (k0 - 608));
    wgf[u] = pack8(s4[0], s4[1]);
}

// ---- kernel 5c: gates partials via MFMA, split-K ----------------------------
__launch_bounds__(256, 4)
__global__ void k_gates(const uint4* __restrict__ xbf,
                        const uint4* __restrict__ wgf,
                        float* __restrict__ gates5) {       // [5][256][2048]
    int tid = threadIdx.x;
    int lane = tid & 63, wave = tid >> 6;
    int l31 = lane & 31, lh = lane >> 5;
    int wid = blockIdx.x * 4 + wave;
    int gI = wid & 63, bI = (wid >> 6) & 7, kI = wid >> 9;

    const short8* ax = (const short8*)xbf + (size_t)(bI * 70 + kI * 14) * 64 + lane;
    const short8* bx = (const short8*)wgf + (size_t)(gI * 70 + kI * 14) * 64 + lane;

    f32x16 acc = {0.f};
#pragma unroll
    for (int c = 0; c < 14; ++c) {
        short8 a = ax[c * 64];
        short8 b = bx[c * 64];
        acc = __builtin_amdgcn_mfma_f32_32x32x16_bf16(a, b, acc, 0, 0, 0);
    }
    float* gout = gates5 + (size_t)kI * (B_ * 2048)
                + (size_t)(bI * 32 + 4 * lh) * 2048 + gI * 32 + l31;
#pragma unroll
    for (int r = 0; r < 16; ++r)
        gout[(size_t)((r & 3) + 8 * (r >> 2)) * 2048] = acc[r];
}

// ---- kernel 6: LSTM pointwise (sums 5 K-slices + biases) --------------------
__global__ void k_lstm(const float* __restrict__ gates5, const float* __restrict__ c,
                       const float* __restrict__ bih, const float* __restrict__ bhh,
                       float* __restrict__ out) {
    int i = blockIdx.x * 256 + threadIdx.x;           // 131072
    int b = i >> 9, u = i & 511;
    size_t base = (size_t)b * 2048 + u;
    float gi = bih[u]        + bhh[u];
    float gf = bih[512 + u]  + bhh[512 + u];
    float gg = bih[1024 + u] + bhh[1024 + u];
    float go = bih[1536 + u] + bhh[1536 + u];
#pragma unroll
    for (int s = 0; s < 5; ++s) {
        const float* g = gates5 + (size_t)s * (B_ * 2048) + base;
        gi += g[0]; gf += g[512]; gg += g[1024]; go += g[1536];
    }
    float si = sigmoid_fast(gi);
    float sf = sigmoid_fast(gf);
    float tg = tanh_fast(gg);
    float so = sigmoid_fast(go);
    float cn = sf * c[i] + si * tg;
    float hn = so * tanh_fast(cn);
    out[i] = hn;                                      // h_new
    out[BT + i] = cn;                                 // c_new
}

extern "C" void kernel_launch(void* const* d_in, const int* in_sizes, int n_in,
                              void* d_out, int out_size, void* d_ws, size_t ws_size,
                              hipStream_t stream) {
    const float* hin  = (const float*)d_in[0];
    const float* c    = (const float*)d_in[1];
    const float* bH   = (const float*)d_in[2];
    const float* oneh = (const float*)d_in[3];
    const float* Wi2h = (const float*)d_in[4];
    const float* Wh2h = (const float*)d_in[5];
    const float* bh2h = (const float*)d_in[6];
    const float* Wsc  = (const float*)d_in[7];
    const float* Wih  = (const float*)d_in[8];
    const float* Whh  = (const float*)d_in[9];
    const float* bih  = (const float*)d_in[10];
    const float* bhh  = (const float*)d_in[11];
    float* out = (float*)d_out;
    float* alpha = out + 2 * BT;                      // output slot 3; also holds e

    // Workspace layout (15.65 MB):
    //   xbf   @ 0         (573,440)     live: xcat .. gates
    //   wgf   @ 573440    (4,587,520)   live: wcat .. gates
    //   --- transient region, dead before k_gates ---
    //   Wbf   @ 5160960   (524,288)
    //   pp    @ 5685248   (524,288)
    //   ctxp  @ 6209536   (4,194,304)
    //   sblk  @ 10403840  (8,192)
    //   invd  @ 10412032  (1,024)
    //   gates5 @ 5160960  (10,485,760)  ALIASES transient region (ends 15,646,720)
    char* w = (char*)d_ws;
    uint4* xbf    = (uint4*)w;
    uint4* wgf    = (uint4*)(w + 573440);
    uint4* Wbf    = (uint4*)(w + 5160960);
    float* pp     = (float*)(w + 5685248);
    float* ctxp   = (float*)(w + 6209536);
    float* sblk   = (float*)(w + 10403840);
    float* invd   = (float*)(w + 10412032);
    float* gates5 = (float*)(w + 5160960);            // aliases Wbf..invd (dead by then)

    k_bswz    <<<128, 256, 0, stream>>>(Wi2h, Wbf);
    k_wcat    <<<1120, 256, 0, stream>>>(Wih, Whh, wgf);
    k_prevproj<<<4096, 256, 0, stream>>>(hin, Wh2h, bh2h, pp);
    k_scores  <<<2048, 512, 0, stream>>>(bH, Wbf, pp, Wsc, alpha, ctxp, sblk);
    k_alpha   <<<512, 256, 0, stream>>>(sblk, alpha, invd);
    k_xcat    <<<140, 256, 0, stream>>>(ctxp, invd, oneh, hin, xbf);
    k_gates   <<<640, 256, 0, stream>>>(xbf, wgf, gates5);
    k_lstm    <<<512, 256, 0, stream>>>(gates5, c, bih, bhh, out);
}